// Round 4
// baseline (491.916 us; speedup 1.0000x reference)
//
#include <hip/hip_runtime.h>
#include <hip/hip_bf16.h>

#define A_NUM 15
#define HDIM 128
#define WDIM 128
#define HW (HDIM*WDIM)
#define PER_IMG (A_NUM*HW)      // 245760
#define NIMG 2
#define PRE_N 6000
#define POST_N 1000
#define NBLK 94                 // ceil(6000/64)
#define NPAD (NBLK*64)          // 6016
#define SORTN 8192
#define CHUNK 2048
#define BLKC 120                // hist blocks per image
#define ITERC 8                 // 256*8 = 2048 elems per hist block

// ws layout (bytes)
#define META_OFF   0u           // [0..1]=selcnt [2..3]=T [4..5]=keepcnt [6..7]=C* [8..9]=cumAbove
#define COARSE_OFF 64u          // 2*120*256*u32 = 245760
#define FINE_OFF   245824u      // 245760
#define SEL_OFF    491584u      // 2*8192*u64 = 131072
#define BOX_OFF    622656u      // 6*2*6016*f32 = 288768
#define VALID_OFF  911424u      // 2*6016*u32 = 48128
#define KEEP_OFF   959552u      // 2*1024*u32 = 8192
#define MASK_OFF   967744u      // 2*6016*94*u64 = 9048064 (end 10,015,808)

__device__ __forceinline__ unsigned int f2ord(float f) {
    unsigned int u = __float_as_uint(f);
    return (u & 0x80000000u) ? ~u : (u | 0x80000000u);
}
__device__ __forceinline__ float ord2f(unsigned int u) {
    unsigned int s = (u & 0x80000000u) ? (u ^ 0x80000000u) : ~u;
    return __uint_as_float(s);
}

// ---------- coarse 256-bin histogram (u>>24), LDS per-wave sub-hists -----
__global__ __launch_bounds__(256) void k_histc(const float* __restrict__ cls,
                                               unsigned int* __restrict__ coarse) {
    __shared__ unsigned int h[4][256];
    int img = blockIdx.y, blk = blockIdx.x;
    int t = threadIdx.x, wv = t >> 6;
    h[0][t] = 0; h[1][t] = 0; h[2][t] = 0; h[3][t] = 0;
    __syncthreads();
    int base = img * PER_IMG + blk * (256 * ITERC);
    #pragma unroll
    for (int it = 0; it < ITERC; ++it) {
        unsigned int u = f2ord(cls[base + it * 256 + t]);
        atomicAdd(&h[wv][u >> 24], 1u);
    }
    __syncthreads();
    coarse[((size_t)img * BLKC + blk) * 256 + t] = h[0][t] + h[1][t] + h[2][t] + h[3][t];
}

// ---------- find coarse bin C* (suffix crosses PRE_N) --------------------
__global__ void k_scanc(const unsigned int* __restrict__ coarse, unsigned int* __restrict__ meta) {
    __shared__ unsigned int tot[256];
    int img = blockIdx.x, b = threadIdx.x;
    const unsigned int* base = coarse + (size_t)img * BLKC * 256;
    unsigned int s = 0;
    for (int k = 0; k < BLKC; ++k) s += base[k * 256 + b];
    tot[b] = s;
    __syncthreads();
    if (b == 0) {
        unsigned int cum = 0; int cstar = 0;
        for (int c = 255; c >= 0; --c) {
            if (cum + tot[c] >= PRE_N) { cstar = c; break; }
            cum += tot[c];
        }
        meta[6 + img] = (unsigned int)cstar;
        meta[8 + img] = cum;
    }
}

// ---------- fine 256-bin histogram within coarse bin C* ------------------
__global__ __launch_bounds__(256) void k_histf(const float* __restrict__ cls,
                                               const unsigned int* __restrict__ meta,
                                               unsigned int* __restrict__ fine) {
    __shared__ unsigned int h[4][256];
    int img = blockIdx.y, blk = blockIdx.x;
    int t = threadIdx.x, wv = t >> 6;
    h[0][t] = 0; h[1][t] = 0; h[2][t] = 0; h[3][t] = 0;
    __syncthreads();
    unsigned int cst = meta[6 + img];
    int base = img * PER_IMG + blk * (256 * ITERC);
    #pragma unroll
    for (int it = 0; it < ITERC; ++it) {
        unsigned int u = f2ord(cls[base + it * 256 + t]);
        if ((u >> 24) == cst) atomicAdd(&h[wv][(u >> 16) & 0xFFu], 1u);
    }
    __syncthreads();
    fine[((size_t)img * BLKC + blk) * 256 + t] = h[0][t] + h[1][t] + h[2][t] + h[3][t];
}

// ---------- final 16-bit threshold T; also reset select counters ---------
__global__ void k_scanf(const unsigned int* __restrict__ fine, unsigned int* __restrict__ meta) {
    __shared__ unsigned int tot[256];
    int img = blockIdx.x, b = threadIdx.x;
    const unsigned int* base = fine + (size_t)img * BLKC * 256;
    unsigned int s = 0;
    for (int k = 0; k < BLKC; ++k) s += base[k * 256 + b];
    tot[b] = s;
    __syncthreads();
    if (b == 0) {
        unsigned int cum = meta[8 + img];
        int fstar = 0;
        for (int f = 255; f >= 0; --f) {
            if (cum + tot[f] >= PRE_N) { fstar = f; break; }
            cum += tot[f];
        }
        meta[2 + img] = (meta[6 + img] << 8) | (unsigned int)fstar;
        meta[img] = 0u;  // reset selcnt for k_gather (every replay)
    }
}

// ---------- gather candidates with 16-bit bin >= T -----------------------
__global__ __launch_bounds__(256) void k_gather(const float* __restrict__ cls,
                                                unsigned int* __restrict__ meta,
                                                unsigned long long* __restrict__ selkeys) {
    int tid = blockIdx.x * blockDim.x + threadIdx.x;   // 0..PER_IMG-1 exactly
    unsigned int T0 = meta[2], T1 = meta[3];
    int a = tid / HW;
    int pos = tid - a * HW;                            // h*WDIM + w
    int m = pos * A_NUM + a;                           // (h,w,a) flattened order
    #pragma unroll
    for (int img = 0; img < NIMG; ++img) {
        unsigned int T = img ? T1 : T0;
        float sc = cls[img * PER_IMG + tid];
        unsigned int u = f2ord(sc);
        bool pred = (u >> 16) >= T;
        unsigned long long mball = __ballot((int)pred);
        if (pred) {
            int lane = (int)(threadIdx.x & 63u);
            int leader = __ffsll(mball) - 1;
            unsigned int basep = 0;
            if (lane == leader)
                basep = atomicAdd(&meta[img], (unsigned int)__popcll(mball));
            basep = (unsigned int)__shfl((int)basep, leader);
            unsigned int p = basep + (unsigned int)__popcll(mball & ((1ULL << lane) - 1ULL));
            if (p < SORTN)
                selkeys[(size_t)img * SORTN + p] =
                    ((unsigned long long)(~u) << 32) | (unsigned int)m;
        }
    }
}

// ---------- multi-block bitonic sort: local 2048-chunk sort --------------
// Chunk c sorted ascending (c even) / descending (c odd) -> global bitonic.
__global__ __launch_bounds__(512) void k_sort_local(unsigned long long* __restrict__ selkeys,
                                                    const unsigned int* __restrict__ meta) {
    __shared__ unsigned long long key[CHUNK];
    int img = blockIdx.x >> 2;
    int c = blockIdx.x & 3;
    unsigned int cnt = meta[img];
    if (cnt > SORTN) cnt = SORTN;
    unsigned long long* g = selkeys + (size_t)img * SORTN;
    int base = c * CHUNK;
    for (int i = threadIdx.x; i < CHUNK; i += 512)
        key[i] = (base + i < (int)cnt) ? g[base + i] : 0xFFFFFFFFFFFFFFFFULL;
    __syncthreads();
    bool desc = (c & 1);
    for (int k = 2; k <= CHUNK; k <<= 1) {
        for (int j = k >> 1; j > 0; j >>= 1) {
            for (int p = threadIdx.x; p < CHUNK / 2; p += 512) {
                int i = ((p & ~(j - 1)) << 1) | (p & (j - 1));
                int x = i | j;
                bool up = (((i & k) == 0) != desc);
                unsigned long long a = key[i], b = key[x];
                if ((a > b) == up) { key[i] = b; key[x] = a; }
            }
            __syncthreads();
        }
    }
    for (int i = threadIdx.x; i < CHUNK; i += 512) g[base + i] = key[i];
}

// ---------- global merge pass (one j per launch) -------------------------
__global__ void k_mg(unsigned long long* __restrict__ selkeys, int k, int j) {
    int p = blockIdx.x * blockDim.x + threadIdx.x;   // SORTN/2 pairs per image
    int img = blockIdx.y;
    unsigned long long* g = selkeys + (size_t)img * SORTN;
    int i = ((p & ~(j - 1)) << 1) | (p & (j - 1));
    int x = i | j;
    bool up = ((i & k) == 0);
    unsigned long long a = g[i], b = g[x];
    if ((a > b) == up) { g[i] = b; g[x] = a; }
}

// ---------- local merge finish (j = 1024..1 in LDS) ----------------------
__global__ __launch_bounds__(512) void k_ml(unsigned long long* __restrict__ selkeys, int k) {
    __shared__ unsigned long long key[CHUNK];
    int img = blockIdx.x >> 2;
    int c = blockIdx.x & 3;
    unsigned long long* g = selkeys + (size_t)img * SORTN;
    int base = c * CHUNK;
    for (int i = threadIdx.x; i < CHUNK; i += 512) key[i] = g[base + i];
    __syncthreads();
    for (int j = CHUNK / 2; j > 0; j >>= 1) {
        for (int p = threadIdx.x; p < CHUNK / 2; p += 512) {
            int li = ((p & ~(j - 1)) << 1) | (p & (j - 1));
            int x = li | j;
            bool up = (((base + li) & k) == 0);
            unsigned long long a = key[li], b = key[x];
            if ((a > b) == up) { key[li] = b; key[x] = a; }
        }
        __syncthreads();
    }
    for (int i = threadIdx.x; i < CHUNK; i += 512) g[base + i] = key[i];
}

// ---------- decode boxes for the sorted top-6000 -------------------------
__global__ void k_decode(const unsigned long long* __restrict__ selkeys,
                         const float* __restrict__ bbox, const float* __restrict__ anchors,
                         const float* __restrict__ iminfo,
                         float* __restrict__ boxsoa, unsigned int* __restrict__ validArr) {
    int r = blockIdx.x * blockDim.x + threadIdx.x;
    int img = blockIdx.y;
    if (r >= PRE_N) return;
    unsigned long long keyv = selkeys[(size_t)img * SORTN + r];
    unsigned int m = (unsigned int)(keyv & 0xFFFFFFFFu);
    unsigned int u = ~(unsigned int)(keyv >> 32);
    float score = ord2f(u);
    int q = m / A_NUM;
    int a = m - q * A_NUM;
    int w = q & (WDIM - 1);
    int h = q >> 7;
    // reference's meshgrid quirk -> x-shift from h, y-shift from w
    float sx = (float)h * 8.0f;
    float sy = (float)w * 8.0f;
    float a0 = __fadd_rn(anchors[a * 4 + 0], sx);
    float a1 = __fadd_rn(anchors[a * 4 + 1], sy);
    float a2 = __fadd_rn(anchors[a * 4 + 2], sx);
    float a3 = __fadd_rn(anchors[a * 4 + 3], sy);
    float ws = __fadd_rn(__fsub_rn(a2, a0), 1.0f);
    float hs = __fadd_rn(__fsub_rn(a3, a1), 1.0f);
    float cx = __fadd_rn(a0, __fmul_rn(0.5f, ws));
    float cy = __fadd_rn(a1, __fmul_rn(0.5f, hs));
    const float* bb = bbox + (size_t)img * 4 * A_NUM * HW;
    int base = h * WDIM + w;
    float dx = bb[(a * 4 + 0) * HW + base];
    float dy = bb[(a * 4 + 1) * HW + base];
    float dwv = bb[(a * 4 + 2) * HW + base];
    float dhv = bb[(a * 4 + 3) * HW + base];
    const float CLIPV = 4.135166556742356f;  // np.float32(log(1000/16))
    float dw = fminf(dwv, CLIPV);
    float dh = fminf(dhv, CLIPV);
    float pcx = __fadd_rn(__fmul_rn(dx, ws), cx);
    float pcy = __fadd_rn(__fmul_rn(dy, hs), cy);
    float pw = __fmul_rn(expf(dw), ws);
    float ph = __fmul_rn(expf(dh), hs);
    float x1 = __fsub_rn(pcx, __fmul_rn(0.5f, pw));
    float y1 = __fsub_rn(pcy, __fmul_rn(0.5f, ph));
    float x2 = __fsub_rn(__fadd_rn(pcx, __fmul_rn(0.5f, pw)), 1.0f);
    float y2 = __fsub_rn(__fadd_rn(pcy, __fmul_rn(0.5f, ph)), 1.0f);
    float him = iminfo[img * 3 + 0], wim = iminfo[img * 3 + 1], scale = iminfo[img * 3 + 2];
    float wmax = __fsub_rn(wim, 1.0f), hmax = __fsub_rn(him, 1.0f);
    x1 = fminf(fmaxf(x1, 0.0f), wmax);
    y1 = fminf(fmaxf(y1, 0.0f), hmax);
    x2 = fminf(fmaxf(x2, 0.0f), wmax);
    y2 = fminf(fmaxf(y2, 0.0f), hmax);
    float bws = __fadd_rn(__fsub_rn(x2, x1), 1.0f);
    float bhs = __fadd_rn(__fsub_rn(y2, y1), 1.0f);
    float minsz = __fmul_rn(0.0f, scale);  // MIN_SIZE * scale
    bool valid = (bws >= minsz) && (bhs >= minsz) &&
                 (__fadd_rn(x1, __fdiv_rn(bws, 2.0f)) < wim) &&
                 (__fadd_rn(y1, __fdiv_rn(bhs, 2.0f)) < him);
    float area = __fmul_rn(bws, bhs);
    boxsoa[(0 * NIMG + img) * NPAD + r] = x1;
    boxsoa[(1 * NIMG + img) * NPAD + r] = y1;
    boxsoa[(2 * NIMG + img) * NPAD + r] = x2;
    boxsoa[(3 * NIMG + img) * NPAD + r] = y2;
    boxsoa[(4 * NIMG + img) * NPAD + r] = area;
    boxsoa[(5 * NIMG + img) * NPAD + r] = score;
    validArr[img * NPAD + r] = valid ? 1u : 0u;
}

// ---------- ROW-major suppression matrix M[img][i][jb], upper tri only ---
// Word M[i][jb] = bits j (in block jb) with iou(i,j) > 0.7, j != i.
// Only tiles jb >= ib(i) are computed; reduce never reads jb < ib.
__global__ __launch_bounds__(256) void k_mask(const float* __restrict__ boxsoa,
                                              unsigned long long* __restrict__ M) {
    int jb = blockIdx.x, ibq = blockIdx.y, img = blockIdx.z;
    if (jb < (ibq << 2)) return;          // whole block below diagonal
    int t = threadIdx.x, wv = t >> 6, lane = t & 63;
    __shared__ float jx1[64], jy1[64], jx2[64], jy2[64], jar[64];
    const float* X1 = boxsoa + (0 * NIMG + img) * NPAD;
    const float* Y1 = boxsoa + (1 * NIMG + img) * NPAD;
    const float* X2 = boxsoa + (2 * NIMG + img) * NPAD;
    const float* Y2 = boxsoa + (3 * NIMG + img) * NPAD;
    const float* AR = boxsoa + (4 * NIMG + img) * NPAD;
    int j0 = jb * 64;
    if (t < 64) {
        int jidx = j0 + t;
        bool jin = jidx < PRE_N;
        jx1[t] = jin ? X1[jidx] : 0.0f;
        jy1[t] = jin ? Y1[jidx] : 0.0f;
        jx2[t] = jin ? X2[jidx] : 0.0f;
        jy2[t] = jin ? Y2[jidx] : 0.0f;
        jar[t] = jin ? AR[jidx] : 1.0f;
    }
    __syncthreads();
    int ib = ibq * 4 + wv;
    if (ib >= NBLK || jb < ib) return;
    int i = ib * 64 + lane;
    unsigned long long bits = 0ULL;
    if (i < PRE_N) {
        float x1 = X1[i], y1 = Y1[i], x2 = X2[i], y2 = Y2[i], ai = AR[i];
        for (int jj = 0; jj < 64; ++jj) {
            int j = j0 + jj;
            if (j == i || j >= PRE_N) continue;
            float ix1 = fmaxf(x1, jx1[jj]);
            float iy1 = fmaxf(y1, jy1[jj]);
            float ix2 = fminf(x2, jx2[jj]);
            float iy2 = fminf(y2, jy2[jj]);
            float iw = fmaxf(__fadd_rn(__fsub_rn(ix2, ix1), 1.0f), 0.0f);
            float ih = fmaxf(__fadd_rn(__fsub_rn(iy2, iy1), 1.0f), 0.0f);
            float inter = __fmul_rn(iw, ih);
            float denom = __fsub_rn(__fadd_rn(ai, jar[jj]), inter);
            float iou = __fdiv_rn(inter, denom);
            if (iou > 0.7f) bits |= (1ULL << jj);
        }
    }
    M[((size_t)img * NPAD + (size_t)i) * NBLK + jb] = bits;
}

// ---------- greedy reduce: one wave per image ----------------------------
// Row-major propagation: kept box k ORs its row M[k][jb] into remv[jb],
// lane t covers consecutive jb -> coalesced.  Diag word prefetched 1 ahead.
__global__ __launch_bounds__(64) void k_reduce(const unsigned long long* __restrict__ M_,
                                               const unsigned int* __restrict__ validArr,
                                               unsigned int* __restrict__ meta,
                                               unsigned int* __restrict__ keeplist) {
    int img = blockIdx.x;
    int t = threadIdx.x;
    __shared__ unsigned long long remv[NBLK];
    __shared__ unsigned short list[POST_N];
    const unsigned long long* M = M_ + (size_t)img * NPAD * NBLK;
    const unsigned int* V = validArr + img * NPAD;
    remv[t] = 0ULL;
    if (t + 64 < NBLK) remv[t + 64] = 0ULL;
    __syncthreads();
    unsigned long long diag_next = M[(size_t)t * NBLK];   // row t, col-block 0
    unsigned int v_next = V[t];
    int cnt = 0;
    for (int ib = 0; ib < NBLK; ++ib) {
        unsigned long long diag = diag_next;
        unsigned int vv = v_next;
        if (ib + 1 < NBLK) {
            int i2 = (ib + 1) * 64 + t;
            diag_next = M[(size_t)i2 * NBLK + (ib + 1)];
            v_next = V[i2];
        }
        int i = ib * 64 + t;
        unsigned long long rw = remv[ib];
        bool alive = (i < PRE_N) && (vv != 0u) && !((rw >> t) & 1ULL);
        unsigned long long keptbits = 0ULL;
        unsigned long long pending = __ballot((int)alive);
        while (pending) {
            int b = __ffsll(pending) - 1;
            keptbits |= 1ULL << b;
            if (t == 0) list[cnt] = (unsigned short)(ib * 64 + b);
            ++cnt;
            if (cnt >= POST_N) break;
            if (t > b && ((diag >> b) & 1ULL)) alive = false;
            pending = __ballot((int)alive) & ~keptbits;
        }
        if (cnt >= POST_N) break;
        if (keptbits) {
            int jb0 = ib + 1 + t;
            int jb1 = jb0 + 64;
            unsigned long long acc0 = 0ULL, acc1 = 0ULL;
            unsigned long long w = keptbits;
            while (w) {
                int b0 = __ffsll(w) - 1; w &= w - 1;
                int b1 = -1, b2 = -1, b3 = -1;
                if (w) { b1 = __ffsll(w) - 1; w &= w - 1; }
                if (w) { b2 = __ffsll(w) - 1; w &= w - 1; }
                if (w) { b3 = __ffsll(w) - 1; w &= w - 1; }
                size_t r0 = (size_t)(ib * 64 + b0) * NBLK;
                size_t r1 = (b1 >= 0) ? (size_t)(ib * 64 + b1) * NBLK : 0;
                size_t r2 = (b2 >= 0) ? (size_t)(ib * 64 + b2) * NBLK : 0;
                size_t r3 = (b3 >= 0) ? (size_t)(ib * 64 + b3) * NBLK : 0;
                if (jb0 < NBLK) {
                    unsigned long long u0 = M[r0 + jb0];
                    unsigned long long u1 = (b1 >= 0) ? M[r1 + jb0] : 0ULL;
                    unsigned long long u2 = (b2 >= 0) ? M[r2 + jb0] : 0ULL;
                    unsigned long long u3 = (b3 >= 0) ? M[r3 + jb0] : 0ULL;
                    acc0 |= u0 | u1 | u2 | u3;
                }
                if (jb1 < NBLK) {
                    unsigned long long u0 = M[r0 + jb1];
                    unsigned long long u1 = (b1 >= 0) ? M[r1 + jb1] : 0ULL;
                    unsigned long long u2 = (b2 >= 0) ? M[r2 + jb1] : 0ULL;
                    unsigned long long u3 = (b3 >= 0) ? M[r3 + jb1] : 0ULL;
                    acc1 |= u0 | u1 | u2 | u3;
                }
            }
            if (jb0 < NBLK) remv[jb0] |= acc0;
            if (jb1 < NBLK) remv[jb1] |= acc1;
        }
        __syncthreads();
    }
    __syncthreads();
    if (t == 0) meta[4 + img] = (unsigned int)cnt;
    for (int k2 = t; k2 < cnt; k2 += 64)
        keeplist[img * 1024 + k2] = (unsigned int)list[k2];
}

// ---------- emit rois + probs --------------------------------------------
__global__ void k_out(const float* __restrict__ boxsoa, const unsigned int* __restrict__ meta,
                      const unsigned int* __restrict__ keeplist, float* __restrict__ out) {
    int k = blockIdx.x * blockDim.x + threadIdx.x;
    int img = blockIdx.y;
    if (k >= POST_N) return;
    unsigned int cnt = meta[4 + img];
    float x1 = 0.0f, y1 = 0.0f, x2 = 0.0f, y2 = 0.0f, sc = -1.0f;
    if (k < (int)cnt) {
        int r = (int)keeplist[img * 1024 + k];
        x1 = boxsoa[(0 * NIMG + img) * NPAD + r];
        y1 = boxsoa[(1 * NIMG + img) * NPAD + r];
        x2 = boxsoa[(2 * NIMG + img) * NPAD + r];
        y2 = boxsoa[(3 * NIMG + img) * NPAD + r];
        sc = boxsoa[(5 * NIMG + img) * NPAD + r];
    }
    float* roi = out + (size_t)(img * POST_N + k) * 5;
    roi[0] = (float)img;
    roi[1] = x1;
    roi[2] = y1;
    roi[3] = x2;
    roi[4] = y2;
    out[NIMG * POST_N * 5 + img * POST_N + k] = sc;
}

extern "C" void kernel_launch(void* const* d_in, const int* in_sizes, int n_in,
                              void* d_out, int out_size, void* d_ws, size_t ws_size,
                              hipStream_t stream) {
    const float* cls = (const float*)d_in[0];
    const float* bbox = (const float*)d_in[1];
    const float* iminfo = (const float*)d_in[2];
    const float* anchors = (const float*)d_in[3];
    float* out = (float*)d_out;
    char* ws = (char*)d_ws;

    unsigned int* meta = (unsigned int*)(ws + META_OFF);
    unsigned int* coarse = (unsigned int*)(ws + COARSE_OFF);
    unsigned int* fine = (unsigned int*)(ws + FINE_OFF);
    unsigned long long* selkeys = (unsigned long long*)(ws + SEL_OFF);
    float* boxsoa = (float*)(ws + BOX_OFF);
    unsigned int* validArr = (unsigned int*)(ws + VALID_OFF);
    unsigned int* keeplist = (unsigned int*)(ws + KEEP_OFF);
    unsigned long long* mask = (unsigned long long*)(ws + MASK_OFF);

    k_histc<<<dim3(BLKC, NIMG), 256, 0, stream>>>(cls, coarse);
    k_scanc<<<NIMG, 256, 0, stream>>>(coarse, meta);
    k_histf<<<dim3(BLKC, NIMG), 256, 0, stream>>>(cls, meta, fine);
    k_scanf<<<NIMG, 256, 0, stream>>>(fine, meta);
    k_gather<<<PER_IMG / 256, 256, 0, stream>>>(cls, meta, selkeys);
    k_sort_local<<<4 * NIMG, 512, 0, stream>>>(selkeys, meta);
    k_mg<<<dim3(SORTN / 2 / 256, NIMG), 256, 0, stream>>>(selkeys, 4096, 2048);
    k_ml<<<4 * NIMG, 512, 0, stream>>>(selkeys, 4096);
    k_mg<<<dim3(SORTN / 2 / 256, NIMG), 256, 0, stream>>>(selkeys, 8192, 4096);
    k_mg<<<dim3(SORTN / 2 / 256, NIMG), 256, 0, stream>>>(selkeys, 8192, 2048);
    k_ml<<<4 * NIMG, 512, 0, stream>>>(selkeys, 8192);
    k_decode<<<dim3((PRE_N + 255) / 256, NIMG), 256, 0, stream>>>(selkeys, bbox, anchors, iminfo,
                                                                  boxsoa, validArr);
    k_mask<<<dim3(NBLK, (NBLK + 3) / 4, NIMG), 256, 0, stream>>>(boxsoa, mask);
    k_reduce<<<NIMG, 64, 0, stream>>>(mask, validArr, meta, keeplist);
    k_out<<<dim3((POST_N + 255) / 256, NIMG), 256, 0, stream>>>(boxsoa, meta, keeplist, out);
}

// Round 5
// 320.610 us; speedup vs baseline: 1.5343x; 1.5343x over previous
//
#include <hip/hip_runtime.h>
#include <hip/hip_bf16.h>

#define A_NUM 15
#define HDIM 128
#define WDIM 128
#define HW (HDIM*WDIM)
#define PER_IMG (A_NUM*HW)      // 245760
#define NIMG 2
#define PRE_N 6000
#define POST_N 1000
#define NBLK 94                 // ceil(6000/64)
#define NPAD (NBLK*64)          // 6016
#define SORTN 8192
#define CHUNK4 4096
#define NBIN 16384

typedef unsigned long long ull;

// ws layout (bytes)
#define META_OFF   0u           // [0..1]=selcnt [2..3]=T(ord16)
#define HIST_OFF   64u          // 2 img * 4 part * 16384 * u16 = 262144
#define SEL_OFF    262208u      // 2*8192*u64 = 131072
#define BOX_OFF    393280u      // 6*2*6016*f32 = 288768
#define VALID_OFF  682048u      // 2*6016*u32 = 48128
#define DIAG_OFF   730176u      // 2*6016*u64 = 96256
#define MASK_OFF   826432u      // 2*6016*94*u64 = 9048064 (end 9,874,496)

__device__ __forceinline__ unsigned int f2ord(float f) {
    unsigned int u = __float_as_uint(f);
    return (u & 0x80000000u) ? ~u : (u | 0x80000000u);
}
__device__ __forceinline__ float ord2f(unsigned int u) {
    unsigned int s = (u & 0x80000000u) ? (u ^ 0x80000000u) : ~u;
    return __uint_as_float(s);
}

// ---------- single-level 16384-bin histogram of ordered bits [30:16] -----
// scores in [0,1) -> ord>>16 in [0x8000, 0xBF80) -> bin = (ord>>16)-0x8000
__global__ __launch_bounds__(1024) void k_hist16(const float* __restrict__ cls,
                                                 unsigned short* __restrict__ hist16) {
    __shared__ unsigned int h[NBIN];
    int img = blockIdx.y, part = blockIdx.x;
    int t = threadIdx.x;
    for (int b = t; b < NBIN; b += 1024) h[b] = 0;
    __syncthreads();
    int base = img * PER_IMG + part * (PER_IMG / 4);
    for (int e = t; e < PER_IMG / 4; e += 1024) {
        unsigned int u = f2ord(cls[base + e]);
        unsigned int bin = (u >> 16) - 0x8000u;
        if (bin > (NBIN - 1)) bin = NBIN - 1;  // safety clamp (impossible for [0,1))
        atomicAdd(&h[bin], 1u);
    }
    __syncthreads();
    unsigned short* outp = hist16 + ((size_t)img * 4 + part) * NBIN;
    for (int b = t; b < NBIN; b += 1024) outp[b] = (unsigned short)h[b];
}

// ---------- parallel suffix-scan: find max bin T with suffix >= PRE_N ----
__global__ __launch_bounds__(1024) void k_scan16(const unsigned short* __restrict__ hist16,
                                                 unsigned int* __restrict__ meta) {
    __shared__ unsigned int csum[1024];
    __shared__ unsigned int aux[64];
    __shared__ unsigned int binv[16];
    int img = blockIdx.x, t = threadIdx.x;
    const unsigned short* hp = hist16 + (size_t)img * 4 * NBIN;
    unsigned int s = 0;
    #pragma unroll
    for (int q = 0; q < 16; ++q) {
        int b = t * 16 + q;
        s += (unsigned)hp[b] + hp[NBIN + b] + hp[2 * NBIN + b] + hp[3 * NBIN + b];
    }
    csum[t] = s;
    __syncthreads();
    if (t < 64) {
        unsigned int x = 0;
        #pragma unroll
        for (int q = 0; q < 16; ++q) x += csum[t * 16 + q];
        aux[t] = x;
    }
    __syncthreads();
    if (t < 64) {
        // suffix over 64 supers (each 256 bins)
        unsigned int suf = 0;
        for (int q = t; q < 64; ++q) suf += aux[q];
        ull mb1 = __ballot(suf >= PRE_N);
        int sstar = 63 - __clzll(mb1);
        unsigned int sufnext = (unsigned)__shfl((int)suf, (sstar + 1) & 63);
        unsigned int cumAbove = (sstar == 63) ? 0u : sufnext;
        // 16 chunks within super
        unsigned int sufC = 0;
        if (t < 16) {
            for (int q = sstar * 16 + t; q < sstar * 16 + 16; ++q) sufC += csum[q];
            sufC += cumAbove;
        }
        ull mb2 = __ballot((t < 16) && (sufC >= PRE_N));
        int crel = 63 - __clzll(mb2);
        int cstar = sstar * 16 + crel;
        unsigned int cumAbove2 = (crel == 15) ? cumAbove : (unsigned)__shfl((int)sufC, crel + 1);
        // 16 bins within chunk
        if (t < 16) {
            int b = cstar * 16 + t;
            binv[t] = (unsigned)hp[b] + hp[NBIN + b] + hp[2 * NBIN + b] + hp[3 * NBIN + b];
        }
        unsigned int sufB = 0;
        if (t < 16) {
            for (int q = t; q < 16; ++q) sufB += binv[q];
            sufB += cumAbove2;
        }
        ull mb3 = __ballot((t < 16) && (sufB >= PRE_N));
        int brel = 63 - __clzll(mb3);
        if (t == 0) {
            meta[2 + img] = (unsigned)(cstar * 16 + brel) + 0x8000u;
            meta[img] = 0u;  // reset select counters for gather (every replay)
        }
    }
}

// ---------- gather candidates with (ord>>16) >= T, block-aggregated ------
__global__ __launch_bounds__(256) void k_gather(const float* __restrict__ cls,
                                                unsigned int* __restrict__ meta,
                                                ull* __restrict__ selkeys) {
    __shared__ unsigned int lcnt[NIMG], lbase[NIMG];
    int t = threadIdx.x;
    int tid = blockIdx.x * 256 + t;
    if (t < NIMG) lcnt[t] = 0;
    __syncthreads();
    unsigned int T0 = meta[2], T1 = meta[3];
    int a = tid / HW;
    int pos = tid - a * HW;          // h*WDIM + w
    int m = pos * A_NUM + a;         // (h,w,a) flattened order
    int lane = t & 63;
    unsigned int uv[NIMG];
    bool pr[NIMG];
    unsigned int lofs[NIMG];
    #pragma unroll
    for (int img = 0; img < NIMG; ++img) {
        unsigned int T = img ? T1 : T0;
        unsigned int u = f2ord(cls[img * PER_IMG + tid]);
        uv[img] = u;
        bool pred = (u >> 16) >= T;
        pr[img] = pred;
        ull mball = __ballot((int)pred);
        unsigned int o = 0;
        if (pred) {
            int leader = __ffsll((long long)mball) - 1;
            unsigned int wbase = 0;
            if (lane == leader) wbase = atomicAdd(&lcnt[img], (unsigned)__popcll(mball));
            wbase = (unsigned)__shfl((int)wbase, leader);
            o = wbase + (unsigned)__popcll(mball & ((1ull << lane) - 1ull));
        }
        lofs[img] = o;
    }
    __syncthreads();
    if (t < NIMG) lbase[t] = atomicAdd(&meta[t], lcnt[t]);
    __syncthreads();
    #pragma unroll
    for (int img = 0; img < NIMG; ++img) {
        if (pr[img]) {
            unsigned int p = lbase[img] + lofs[img];
            if (p < SORTN)
                selkeys[(size_t)img * SORTN + p] =
                    ((ull)(~uv[img]) << 32) | (unsigned int)m;
        }
    }
}

// ---------- bitonic: local sort of 4096-chunks (asc/desc) ----------------
__global__ __launch_bounds__(512) void k_sortA(ull* __restrict__ selkeys,
                                               const unsigned int* __restrict__ meta) {
    __shared__ ull key[CHUNK4];   // 32 KB
    int img = blockIdx.x >> 1, c = blockIdx.x & 1;
    unsigned int cnt = meta[img];
    if (cnt > SORTN) cnt = SORTN;
    ull* g = selkeys + (size_t)img * SORTN;
    int base = c * CHUNK4;
    for (int i = threadIdx.x; i < CHUNK4; i += 512)
        key[i] = (base + i < (int)cnt) ? g[base + i] : ~0ull;
    __syncthreads();
    bool desc = (c & 1);
    for (int k = 2; k <= CHUNK4; k <<= 1) {
        for (int j = k >> 1; j > 0; j >>= 1) {
            for (int p = threadIdx.x; p < CHUNK4 / 2; p += 512) {
                int i = ((p & ~(j - 1)) << 1) | (p & (j - 1));
                int x = i | j;
                bool up = (((i & k) == 0) != desc);
                ull A = key[i], B = key[x];
                if ((A > B) == up) { key[i] = B; key[x] = A; }
            }
            __syncthreads();
        }
    }
    for (int i = threadIdx.x; i < CHUNK4; i += 512) g[base + i] = key[i];
}

// ---------- bitonic: final k=8192 merge in one 64KB-LDS block ------------
__global__ __launch_bounds__(512) void k_sortC(ull* __restrict__ selkeys) {
    __shared__ ull key[SORTN];    // 64 KB
    int img = blockIdx.x;
    ull* g = selkeys + (size_t)img * SORTN;
    for (int i = threadIdx.x; i < SORTN; i += 512) key[i] = g[i];
    __syncthreads();
    for (int j = SORTN / 2; j > 0; j >>= 1) {
        for (int p = threadIdx.x; p < SORTN / 2; p += 512) {
            int i = ((p & ~(j - 1)) << 1) | (p & (j - 1));
            int x = i | j;
            ull A = key[i], B = key[x];   // k=8192 -> ascending everywhere
            if (A > B) { key[i] = B; key[x] = A; }
        }
        __syncthreads();
    }
    for (int i = threadIdx.x; i < PRE_N; i += 512) g[i] = key[i];
}

// ---------- decode boxes for the sorted top-6000 -------------------------
__global__ void k_decode(const ull* __restrict__ selkeys,
                         const float* __restrict__ bbox, const float* __restrict__ anchors,
                         const float* __restrict__ iminfo,
                         float* __restrict__ boxsoa, unsigned int* __restrict__ validArr) {
    int r = blockIdx.x * blockDim.x + threadIdx.x;
    int img = blockIdx.y;
    if (r >= PRE_N) return;
    ull keyv = selkeys[(size_t)img * SORTN + r];
    unsigned int m = (unsigned int)(keyv & 0xFFFFFFFFu);
    unsigned int u = ~(unsigned int)(keyv >> 32);
    float score = ord2f(u);
    int q = m / A_NUM;
    int a = m - q * A_NUM;
    int w = q & (WDIM - 1);
    int h = q >> 7;
    // reference's meshgrid quirk -> x-shift from h, y-shift from w
    float sx = (float)h * 8.0f;
    float sy = (float)w * 8.0f;
    float a0 = __fadd_rn(anchors[a * 4 + 0], sx);
    float a1 = __fadd_rn(anchors[a * 4 + 1], sy);
    float a2 = __fadd_rn(anchors[a * 4 + 2], sx);
    float a3 = __fadd_rn(anchors[a * 4 + 3], sy);
    float ws = __fadd_rn(__fsub_rn(a2, a0), 1.0f);
    float hs = __fadd_rn(__fsub_rn(a3, a1), 1.0f);
    float cx = __fadd_rn(a0, __fmul_rn(0.5f, ws));
    float cy = __fadd_rn(a1, __fmul_rn(0.5f, hs));
    const float* bb = bbox + (size_t)img * 4 * A_NUM * HW;
    int base = h * WDIM + w;
    float dx = bb[(a * 4 + 0) * HW + base];
    float dy = bb[(a * 4 + 1) * HW + base];
    float dwv = bb[(a * 4 + 2) * HW + base];
    float dhv = bb[(a * 4 + 3) * HW + base];
    const float CLIPV = 4.135166556742356f;  // np.float32(log(1000/16))
    float dw = fminf(dwv, CLIPV);
    float dh = fminf(dhv, CLIPV);
    float pcx = __fadd_rn(__fmul_rn(dx, ws), cx);
    float pcy = __fadd_rn(__fmul_rn(dy, hs), cy);
    float pw = __fmul_rn(expf(dw), ws);
    float ph = __fmul_rn(expf(dh), hs);
    float x1 = __fsub_rn(pcx, __fmul_rn(0.5f, pw));
    float y1 = __fsub_rn(pcy, __fmul_rn(0.5f, ph));
    float x2 = __fsub_rn(__fadd_rn(pcx, __fmul_rn(0.5f, pw)), 1.0f);
    float y2 = __fsub_rn(__fadd_rn(pcy, __fmul_rn(0.5f, ph)), 1.0f);
    float him = iminfo[img * 3 + 0], wim = iminfo[img * 3 + 1], scale = iminfo[img * 3 + 2];
    float wmax = __fsub_rn(wim, 1.0f), hmax = __fsub_rn(him, 1.0f);
    x1 = fminf(fmaxf(x1, 0.0f), wmax);
    y1 = fminf(fmaxf(y1, 0.0f), hmax);
    x2 = fminf(fmaxf(x2, 0.0f), wmax);
    y2 = fminf(fmaxf(y2, 0.0f), hmax);
    float bws = __fadd_rn(__fsub_rn(x2, x1), 1.0f);
    float bhs = __fadd_rn(__fsub_rn(y2, y1), 1.0f);
    float minsz = __fmul_rn(0.0f, scale);  // MIN_SIZE * scale
    bool valid = (bws >= minsz) && (bhs >= minsz) &&
                 (__fadd_rn(x1, __fdiv_rn(bws, 2.0f)) < wim) &&
                 (__fadd_rn(y1, __fdiv_rn(bhs, 2.0f)) < him);
    float area = __fmul_rn(bws, bhs);
    boxsoa[(0 * NIMG + img) * NPAD + r] = x1;
    boxsoa[(1 * NIMG + img) * NPAD + r] = y1;
    boxsoa[(2 * NIMG + img) * NPAD + r] = x2;
    boxsoa[(3 * NIMG + img) * NPAD + r] = y2;
    boxsoa[(4 * NIMG + img) * NPAD + r] = area;
    boxsoa[(5 * NIMG + img) * NPAD + r] = score;
    validArr[img * NPAD + r] = valid ? 1u : 0u;
}

// ---------- ROW-major suppression matrix M[img][i][jb] (jb>=ib) + diag ---
__global__ __launch_bounds__(256) void k_mask(const float* __restrict__ boxsoa,
                                              ull* __restrict__ M,
                                              ull* __restrict__ diagArr) {
    int jb = blockIdx.x, ibq = blockIdx.y, img = blockIdx.z;
    if (jb < (ibq << 2)) return;          // whole quad below diagonal
    int t = threadIdx.x, wv = t >> 6, lane = t & 63;
    __shared__ float jx1[64], jy1[64], jx2[64], jy2[64], jar[64];
    const float* X1 = boxsoa + (0 * NIMG + img) * NPAD;
    const float* Y1 = boxsoa + (1 * NIMG + img) * NPAD;
    const float* X2 = boxsoa + (2 * NIMG + img) * NPAD;
    const float* Y2 = boxsoa + (3 * NIMG + img) * NPAD;
    const float* AR = boxsoa + (4 * NIMG + img) * NPAD;
    int j0 = jb * 64;
    if (t < 64) {
        int jidx = j0 + t;
        bool jin = jidx < PRE_N;
        jx1[t] = jin ? X1[jidx] : 0.0f;
        jy1[t] = jin ? Y1[jidx] : 0.0f;
        jx2[t] = jin ? X2[jidx] : 0.0f;
        jy2[t] = jin ? Y2[jidx] : 0.0f;
        jar[t] = jin ? AR[jidx] : 1.0f;
    }
    __syncthreads();
    int ib = ibq * 4 + wv;
    if (ib >= NBLK || jb < ib) return;
    int i = ib * 64 + lane;
    ull bits = 0ULL;
    if (i < PRE_N) {
        float x1 = X1[i], y1 = Y1[i], x2 = X2[i], y2 = Y2[i], ai = AR[i];
        for (int jj = 0; jj < 64; ++jj) {
            int j = j0 + jj;
            if (j == i || j >= PRE_N) continue;
            float ix1 = fmaxf(x1, jx1[jj]);
            float iy1 = fmaxf(y1, jy1[jj]);
            float ix2 = fminf(x2, jx2[jj]);
            float iy2 = fminf(y2, jy2[jj]);
            float iw = fmaxf(__fadd_rn(__fsub_rn(ix2, ix1), 1.0f), 0.0f);
            float ih = fmaxf(__fadd_rn(__fsub_rn(iy2, iy1), 1.0f), 0.0f);
            float inter = __fmul_rn(iw, ih);
            float denom = __fsub_rn(__fadd_rn(ai, jar[jj]), inter);
            float iou = __fdiv_rn(inter, denom);
            if (iou > 0.7f) bits |= (1ULL << jj);
        }
    }
    M[((size_t)img * NPAD + (size_t)i) * NBLK + jb] = bits;
    if (jb == ib) diagArr[(size_t)img * NPAD + i] = bits;
}

// ---------- greedy reduce + output emit: one wave per image --------------
// remv held in lane-owned registers (lane t owns jb=t and jb=t+64).
// Greedy chain: scalar ffs + readlane on register diag rows (~30cyc/kept).
// Propagation: 8-kept batches of coalesced row loads, 1 waitcnt per batch.
__global__ __launch_bounds__(64, 1) void k_reduce(const ull* __restrict__ M_,
                                                  const ull* __restrict__ diagArr,
                                                  const unsigned int* __restrict__ validArr,
                                                  const float* __restrict__ boxsoa,
                                                  float* __restrict__ out) {
    int img = blockIdx.x;
    int t = threadIdx.x;
    __shared__ ull s_keptw[NBLK];
    __shared__ unsigned short s_base[NBLK];
    __shared__ unsigned short s_list[POST_N];
    const ull* M = M_ + (size_t)img * NPAD * NBLK;
    const ull* D = diagArr + (size_t)img * NPAD;
    const unsigned int* V = validArr + img * NPAD;
    s_keptw[t] = 0ULL;
    if (t + 64 < NBLK) s_keptw[t + 64] = 0ULL;
    // lane-owned remv registers
    unsigned int r0lo = 0, r0hi = 0, r1lo = 0, r1hi = 0;
    // prefetch block 0
    ull d_cur = D[t];
    bool v_cur = (t < PRE_N) && (V[t] != 0u);
    int cnt = 0;
    for (int ib = 0; ib < NBLK; ++ib) {
        // prefetch next block's diag + valid (coalesced, 1 step of slack)
        ull d_nxt = 0ULL;
        bool v_nxt = false;
        if (ib + 1 < NBLK) {
            int i2 = (ib + 1) * 64 + t;
            d_nxt = D[i2];
            v_nxt = (i2 < PRE_N) && (V[i2] != 0u);
        }
        ull validw = __ballot((int)v_cur);
        // this block's suppression word from lane-owned regs
        unsigned int slo, shi;
        if (ib < 64) {
            slo = (unsigned)__builtin_amdgcn_readlane((int)r0lo, ib);
            shi = (unsigned)__builtin_amdgcn_readlane((int)r0hi, ib);
        } else {
            slo = (unsigned)__builtin_amdgcn_readlane((int)r1lo, ib - 64);
            shi = (unsigned)__builtin_amdgcn_readlane((int)r1hi, ib - 64);
        }
        ull sup = ((ull)shi << 32) | slo;
        ull live = validw & ~sup;
        if (t == 0) s_base[ib] = (unsigned short)cnt;
        unsigned int dlo = (unsigned int)d_cur, dhi = (unsigned int)(d_cur >> 32);
        ull keptb = 0ULL;
        while (live) {
            int b = __ffsll((long long)live) - 1;
            keptb |= 1ULL << b;
            ++cnt;
            if (cnt >= POST_N) break;
            unsigned int rl = (unsigned)__builtin_amdgcn_readlane((int)dlo, b);
            unsigned int rh = (unsigned)__builtin_amdgcn_readlane((int)dhi, b);
            ull row = ((ull)rh << 32) | rl;
            live &= ~row;
            live &= ~(1ULL << b);
        }
        if (t == 0) s_keptw[ib] = keptb;
        if (cnt >= POST_N) break;
        // propagate kept rows into lane-owned remv (coalesced, batched)
        if (keptb) {
            ull w = keptb;
            while (w) {
                const ull* rp[8];
                #pragma unroll
                for (int q = 0; q < 8; ++q) {
                    if (w) {
                        int b = __ffsll((long long)w) - 1;
                        w &= w - 1;
                        rp[q] = M + (size_t)(ib * 64 + b) * NBLK;
                    } else rp[q] = nullptr;
                }
                ull v0[8], v1[8];
                #pragma unroll
                for (int q = 0; q < 8; ++q) {
                    v0[q] = rp[q] ? rp[q][t] : 0ULL;
                    v1[q] = (rp[q] && t + 64 < NBLK) ? rp[q][t + 64] : 0ULL;
                }
                ull a0 = 0ULL, a1 = 0ULL;
                #pragma unroll
                for (int q = 0; q < 8; ++q) { a0 |= v0[q]; a1 |= v1[q]; }
                r0lo |= (unsigned int)a0; r0hi |= (unsigned int)(a0 >> 32);
                r1lo |= (unsigned int)a1; r1hi |= (unsigned int)(a1 >> 32);
            }
        }
        d_cur = d_nxt;
        v_cur = v_nxt;
    }
    int total = cnt > POST_N ? POST_N : cnt;
    // expand keptw words -> ordered list positions (parallel over blocks)
    for (int ib = t; ib < NBLK; ib += 64) {
        ull w = s_keptw[ib];
        int pos = s_base[ib];
        while (w) {
            int b = __ffsll((long long)w) - 1;
            w &= w - 1;
            if (pos < POST_N) s_list[pos] = (unsigned short)(ib * 64 + b);
            ++pos;
        }
    }
    // emit rois + probs (single wave: LDS writes above are program-ordered)
    for (int k = t; k < POST_N; k += 64) {
        float x1 = 0.0f, y1 = 0.0f, x2 = 0.0f, y2 = 0.0f, sc = -1.0f;
        if (k < total) {
            int r = (int)s_list[k];
            x1 = boxsoa[(0 * NIMG + img) * NPAD + r];
            y1 = boxsoa[(1 * NIMG + img) * NPAD + r];
            x2 = boxsoa[(2 * NIMG + img) * NPAD + r];
            y2 = boxsoa[(3 * NIMG + img) * NPAD + r];
            sc = boxsoa[(5 * NIMG + img) * NPAD + r];
        }
        float* roi = out + (size_t)(img * POST_N + k) * 5;
        roi[0] = (float)img;
        roi[1] = x1;
        roi[2] = y1;
        roi[3] = x2;
        roi[4] = y2;
        out[NIMG * POST_N * 5 + img * POST_N + k] = sc;
    }
}

extern "C" void kernel_launch(void* const* d_in, const int* in_sizes, int n_in,
                              void* d_out, int out_size, void* d_ws, size_t ws_size,
                              hipStream_t stream) {
    const float* cls = (const float*)d_in[0];
    const float* bbox = (const float*)d_in[1];
    const float* iminfo = (const float*)d_in[2];
    const float* anchors = (const float*)d_in[3];
    float* out = (float*)d_out;
    char* ws = (char*)d_ws;

    unsigned int* meta = (unsigned int*)(ws + META_OFF);
    unsigned short* hist16 = (unsigned short*)(ws + HIST_OFF);
    ull* selkeys = (ull*)(ws + SEL_OFF);
    float* boxsoa = (float*)(ws + BOX_OFF);
    unsigned int* validArr = (unsigned int*)(ws + VALID_OFF);
    ull* diagArr = (ull*)(ws + DIAG_OFF);
    ull* mask = (ull*)(ws + MASK_OFF);

    k_hist16<<<dim3(4, NIMG), 1024, 0, stream>>>(cls, hist16);
    k_scan16<<<NIMG, 1024, 0, stream>>>(hist16, meta);
    k_gather<<<PER_IMG / 256, 256, 0, stream>>>(cls, meta, selkeys);
    k_sortA<<<2 * NIMG, 512, 0, stream>>>(selkeys, meta);
    k_sortC<<<NIMG, 512, 0, stream>>>(selkeys);
    k_decode<<<dim3((PRE_N + 255) / 256, NIMG), 256, 0, stream>>>(selkeys, bbox, anchors, iminfo,
                                                                  boxsoa, validArr);
    k_mask<<<dim3(NBLK, (NBLK + 3) / 4, NIMG), 256, 0, stream>>>(boxsoa, mask, diagArr);
    k_reduce<<<NIMG, 64, 0, stream>>>(mask, diagArr, validArr, boxsoa, out);
}